// Round 2
// baseline (351.822 us; speedup 1.0000x reference)
//
#include <hip/hip_runtime.h>

using f16   = _Float16;
using f16x8 = __attribute__((ext_vector_type(8))) _Float16;
using f32x4 = __attribute__((ext_vector_type(4))) float;
using u32x4 = __attribute__((ext_vector_type(4))) unsigned int;

#define MFMA16(a, b, c) __builtin_amdgcn_mfma_f32_16x16x32_f16((a), (b), (c), 0, 0, 0)

namespace {
constexpr int kT = 8, kWd = 14, kS = 196;
constexpr int kN = 1568;      // T*S (sequence length per batch)
constexpr int kM = 3136;      // B*N (GEMM rows)
constexpr int kHeads = 12;
constexpr int kNp = 1664;     // padded N (13*128)
// workspace byte offsets (all 256-aligned)
constexpr size_t OFF_Q    = 0;                       // qf  [24][Np][64] f16 (unscaled q)
constexpr size_t OFF_QE   = 5111808;                 // qe  [24][Np][64] f16 (rel ext, dims 0..36 valid)
constexpr size_t OFF_K    = 10223616;                // kf  [24][Np][64] f16 (k * 0.125)
constexpr size_t OFF_KONE = 15335424;                // kone[Np][64] f16 (one-hot ext, bh-independent)
constexpr size_t OFF_V    = 15548416;                // vT  [24][64][Np] f16
constexpr size_t OFF_O    = 20660224;                // Of  [3200][768] f16
constexpr size_t WS_TOTAL = 25575424;
}

// ---------------- QKV GEMM: C[3136,2304] = X[3136,768] @ W[2304,768]^T ----------
// epilogue scatters q (unscaled), k*scale, v^T per head (f16, padded rows NOT zeroed)
__global__ __launch_bounds__(256) void arp_gemm_qkv(
    const float* __restrict__ X, const float* __restrict__ W,
    f16* __restrict__ qf, f16* __restrict__ kf, f16* __restrict__ vT) {
  __shared__ f16 sA[128 * 40];
  __shared__ f16 sB[128 * 40];
  const int tid = threadIdx.x, lane = tid & 63, wv = tid >> 6;
  const int m0 = blockIdx.y * 128, n0 = blockIdx.x * 128;
  const int wm = (wv & 1) * 64, wn = (wv >> 1) * 64;
  const int frow = lane & 15, fcol = (lane >> 4) * 8;
  const f32x4 vzero = {0.f, 0.f, 0.f, 0.f};
  f32x4 acc[4][4];
  for (int i = 0; i < 4; ++i)
    for (int j = 0; j < 4; ++j) acc[i][j] = vzero;

  for (int kt = 0; kt < 24; ++kt) {  // K=768, BK=32
#pragma unroll
    for (int i = 0; i < 4; ++i) {
      int idx = i * 256 + tid;
      int r = idx >> 3, c4 = (idx & 7) * 4;
      float4 v = {0.f, 0.f, 0.f, 0.f};
      int gm = m0 + r;
      if (gm < kM) v = *(const float4*)(X + (size_t)gm * 768 + kt * 32 + c4);
      f16* dst = &sA[r * 40 + c4];
      dst[0] = (f16)v.x; dst[1] = (f16)v.y; dst[2] = (f16)v.z; dst[3] = (f16)v.w;
    }
#pragma unroll
    for (int i = 0; i < 4; ++i) {
      int idx = i * 256 + tid;
      int r = idx >> 3, c4 = (idx & 7) * 4;
      float4 v = *(const float4*)(W + (size_t)(n0 + r) * 768 + kt * 32 + c4);
      f16* dst = &sB[r * 40 + c4];
      dst[0] = (f16)v.x; dst[1] = (f16)v.y; dst[2] = (f16)v.z; dst[3] = (f16)v.w;
    }
    __syncthreads();
    f16x8 af[4], bf[4];
#pragma unroll
    for (int t = 0; t < 4; ++t) {
      af[t] = *(const f16x8*)&sA[(wm + t * 16 + frow) * 40 + fcol];
      bf[t] = *(const f16x8*)&sB[(wn + t * 16 + frow) * 40 + fcol];
    }
#pragma unroll
    for (int mt = 0; mt < 4; ++mt)
#pragma unroll
      for (int nt = 0; nt < 4; ++nt)
        acc[mt][nt] = MFMA16(af[mt], bf[nt], acc[mt][nt]);
    __syncthreads();
  }
#pragma unroll
  for (int mt = 0; mt < 4; ++mt) {
    int rbase = m0 + wm + mt * 16 + (lane >> 4) * 4;
#pragma unroll
    for (int nt = 0; nt < 4; ++nt) {
      int col0 = n0 + wn + nt * 16;        // multiple of 16, uniform per nt
      int which = col0 / 768;
      int rem = col0 - which * 768;
      int hh = rem >> 6;
      int d = (rem & 63) + frow;
#pragma unroll
      for (int rg = 0; rg < 4; ++rg) {
        int m = rbase + rg;
        if (m < kM) {
          int b = (m >= kN) ? 1 : 0;
          int ns = m - b * kN;
          int bh = b * kHeads + hh;
          float av = acc[mt][nt][rg];
          if (which == 1) av *= 0.125f;      // fold softmax scale into K
          f16 hv = (f16)av;
          if (which == 0)      qf[((size_t)bh * kNp + ns) * 64 + d] = hv;
          else if (which == 1) kf[((size_t)bh * kNp + ns) * 64 + d] = hv;
          else                 vT[((size_t)bh * 64 + d) * kNp + ns] = hv;
        }
      }
    }
  }
}

// ---------------- K one-hot extension (bh-independent): kone[n][64] -------------
// dims 0..13 = onehot(h2), 14..27 = onehot(w2), 28..35 = onehot(t2),
// dim 36 = 1 if key padded (n>=kN) else 0, dims 37..63 = 0.
__global__ __launch_bounds__(256) void arp_kone(f16* __restrict__ kone) {
  int tid = blockIdx.x * 256 + threadIdx.x;
  if (tid >= kNp * 64) return;
  int n = tid >> 6, c = tid & 63;
  int t2 = n / kS; int rm = n - t2 * kS;
  int h2 = rm / kWd; int w2 = rm - h2 * kWd;
  if (t2 > kT - 1) t2 = kT - 1;
  float v = 0.f;
  if (c == h2) v = 1.f;
  else if (c == 14 + w2) v = 1.f;
  else if (c == 28 + t2) v = 1.f;
  else if (c == 36 && n >= kN) v = 1.f;
  kone[tid] = (f16)v;
}

// ---------------- Q extension: qe[bh][q][e] = q_vec . rel_pos[idx], e<36 --------
// e==36: constant -1e4 (pairs with kone validity slot -> masks padded keys)
__global__ __launch_bounds__(256) void arp_qext(
    const f16* __restrict__ qf,
    const float* __restrict__ Rh, const float* __restrict__ Rw, const float* __restrict__ Rt,
    f16* __restrict__ qe) {
  int tid = blockIdx.x * 256 + threadIdx.x;
  const int TOT = 24 * kN * 37;
  if (tid >= TOT) return;
  int e = tid % 37;
  int rem = tid / 37;
  int q = rem % kN;
  int bh = rem / kN;
  f16* out = qe + ((size_t)bh * kNp + q) * 64;
  if (e == 36) { out[36] = (f16)(-10000.f); return; }
  int tq = q / kS, sr = q - tq * kS;
  int hq = sr / kWd, wq = sr - hq * kWd;
  const float* R;
  if (e < 14)      R = Rh + (hq - e + 13) * 64;
  else if (e < 28) R = Rw + (wq - (e - 14) + 13) * 64;
  else             R = Rt + (tq - (e - 28) + 7) * 64;
  const f16* qv = qf + ((size_t)bh * kNp + q) * 64;
  float sum = 0.f;
#pragma unroll
  for (int c = 0; c < 64; ++c) sum += (float)qv[c] * R[c];
  out[e] = (f16)sum;
}

// ---------------- flash attention, bias folded into QK^T via ext dims -----------
// grid (25 q-tiles of 64, 24 bh); K_ext = 128 dims -> 4 MFMA k-steps.
// LDS: sK 34816 + sP 17408 = 52224 B -> 3 blocks/CU; V frags read from global.
__global__ __launch_bounds__(256, 3) void arp_attn(
    const f16* __restrict__ qf, const f16* __restrict__ qe,
    const f16* __restrict__ kf, const f16* __restrict__ kone,
    const f16* __restrict__ vT, f16* __restrict__ Of) {
  __shared__ f16 sK[128 * 136];       // [key][136] valid 128 (64 k + 64 ext)
  __shared__ f16 sP[4][16 * 136];     // per-wave P round-trip

  const int tid = threadIdx.x, lane = tid & 63, wv = tid >> 6;
  const int q0 = blockIdx.x * 64;
  const int bh = blockIdx.y;
  const int b = bh / kHeads, hh = bh - b * kHeads;
  const int frow = lane & 15, quad = lane >> 4;
  const f32x4 vzero = {0.f, 0.f, 0.f, 0.f};

  // persistent Q_ext fragments (A-layout), rows q0 + wv*16 + frow
  f16x8 aQ[4];
  {
    int row = q0 + wv * 16 + frow;
    const f16* qp = qf + ((size_t)bh * kNp + row) * 64;
    aQ[0] = *(const f16x8*)(qp + quad * 8);
    aQ[1] = *(const f16x8*)(qp + 32 + quad * 8);
    const f16* ep = qe + ((size_t)bh * kNp + row) * 64;
    aQ[2] = *(const f16x8*)(ep + quad * 8);
    aQ[3] = *(const f16x8*)(ep + 32 + quad * 8);
  }
  float m_i[4], l_i[4], alpha[4];
  f32x4 Oc[4];
#pragma unroll
  for (int r = 0; r < 4; ++r) { m_i[r] = -__builtin_inff(); l_i[r] = 0.f; }
#pragma unroll
  for (int t = 0; t < 4; ++t) Oc[t] = vzero;

  const f16* vb = vT + (size_t)bh * 64 * kNp;

  for (int kt = 0; kt < 13; ++kt) {
    __syncthreads();
    // stage K_ext tile [128][128] -> sK (cols 0..63 from kf, 64..127 from kone)
#pragma unroll
    for (int i = 0; i < 8; ++i) {
      int idx = i * 256 + tid;
      int r = idx >> 4, ch = idx & 15;
      const f16* src = (ch < 8)
          ? kf + ((size_t)bh * kNp + kt * 128 + r) * 64 + ch * 8
          : kone + (size_t)(kt * 128 + r) * 64 + (ch - 8) * 8;
      *(u32x4*)&sK[r * 136 + ch * 8] = *(const u32x4*)src;
    }
    __syncthreads();

    // QK^T + bias in one shot: S[16 x 128] per wave, K=128
    f32x4 Sc[8];
#pragma unroll
    for (int nt = 0; nt < 8; ++nt) {
      const f16* kb = &sK[(nt * 16 + frow) * 136 + quad * 8];
      f32x4 s = MFMA16(aQ[0], *(const f16x8*)(kb), vzero);
      s = MFMA16(aQ[1], *(const f16x8*)(kb + 32), s);
      s = MFMA16(aQ[2], *(const f16x8*)(kb + 64), s);
      Sc[nt] = MFMA16(aQ[3], *(const f16x8*)(kb + 96), s);
    }
    // online softmax per row (scale+bias+mask already inside Sc)
    float pv[8][4];
#pragma unroll
    for (int nt = 0; nt < 8; ++nt)
#pragma unroll
      for (int r = 0; r < 4; ++r) pv[nt][r] = Sc[nt][r];
#pragma unroll
    for (int r = 0; r < 4; ++r) {
      float mx = pv[0][r];
#pragma unroll
      for (int nt = 1; nt < 8; ++nt) mx = fmaxf(mx, pv[nt][r]);
#pragma unroll
      for (int off = 1; off < 16; off <<= 1) mx = fmaxf(mx, __shfl_xor(mx, off, 64));
      float mn = fmaxf(m_i[r], mx);
      alpha[r] = __expf(m_i[r] - mn);
      m_i[r] = mn;
      float rs = 0.f;
#pragma unroll
      for (int nt = 0; nt < 8; ++nt) {
        float p = __expf(pv[nt][r] - mn);
        pv[nt][r] = p;
        rs += p;
      }
#pragma unroll
      for (int off = 1; off < 16; off <<= 1) rs += __shfl_xor(rs, off, 64);
      l_i[r] = l_i[r] * alpha[r] + rs;
    }
#pragma unroll
    for (int t = 0; t < 4; ++t) {
      Oc[t][0] *= alpha[0]; Oc[t][1] *= alpha[1];
      Oc[t][2] *= alpha[2]; Oc[t][3] *= alpha[3];
    }
    // issue V-fragment global loads (independent of the LDS ops below)
    f16x8 bV[4][4];
#pragma unroll
    for (int kc = 0; kc < 4; ++kc)
#pragma unroll
      for (int t = 0; t < 4; ++t)
        bV[kc][t] = *(const f16x8*)(vb + (size_t)(t * 16 + frow) * kNp
                                    + kt * 128 + kc * 32 + quad * 8);
    // P: C-layout -> LDS -> A-layout (per-wave buffer, intra-wave dep only)
#pragma unroll
    for (int nt = 0; nt < 8; ++nt)
#pragma unroll
      for (int r = 0; r < 4; ++r)
        sP[wv][(quad * 4 + r) * 136 + nt * 16 + frow] = (f16)pv[nt][r];
    // PV: O[16 x 64] += P[16 x 128] @ V[128 x 64]
#pragma unroll
    for (int kc = 0; kc < 4; ++kc) {
      f16x8 aP = *(const f16x8*)&sP[wv][frow * 136 + kc * 32 + quad * 8];
#pragma unroll
      for (int t = 0; t < 4; ++t)
        Oc[t] = MFMA16(aP, bV[kc][t], Oc[t]);
    }
  }
  // epilogue: normalize and store O[b*N+row][hh*64 + d] as f16
#pragma unroll
  for (int t = 0; t < 4; ++t)
#pragma unroll
    for (int r = 0; r < 4; ++r) {
      int row = q0 + wv * 16 + quad * 4 + r;
      if (row < kN) {
        float val = Oc[t][r] / l_i[r];
        Of[((size_t)(b * kN + row)) * 768 + hh * 64 + t * 16 + frow] = (f16)val;
      }
    }
}

// ---------------- proj GEMM: out[3136,768] = O[3136,768] @ Wp[768,768]^T + bias --
__global__ __launch_bounds__(256) void arp_gemm_proj(
    const f16* __restrict__ A, const float* __restrict__ W,
    const float* __restrict__ bias, float* __restrict__ out) {
  __shared__ f16 sA[128 * 40];
  __shared__ f16 sB[128 * 40];
  const int tid = threadIdx.x, lane = tid & 63, wv = tid >> 6;
  const int m0 = blockIdx.y * 128, n0 = blockIdx.x * 128;
  const int wm = (wv & 1) * 64, wn = (wv >> 1) * 64;
  const int frow = lane & 15, fcol = (lane >> 4) * 8;
  const f32x4 vzero = {0.f, 0.f, 0.f, 0.f};
  f32x4 acc[4][4];
  for (int i = 0; i < 4; ++i)
    for (int j = 0; j < 4; ++j) acc[i][j] = vzero;

  for (int kt = 0; kt < 24; ++kt) {
#pragma unroll
    for (int i = 0; i < 2; ++i) {
      int idx = i * 256 + tid;
      int r = idx >> 2, c8 = (idx & 3) * 8;
      u32x4 v = *(const u32x4*)(A + (size_t)(m0 + r) * 768 + kt * 32 + c8);
      *(u32x4*)&sA[r * 40 + c8] = v;
    }
#pragma unroll
    for (int i = 0; i < 4; ++i) {
      int idx = i * 256 + tid;
      int r = idx >> 3, c4 = (idx & 7) * 4;
      float4 v = *(const float4*)(W + (size_t)(n0 + r) * 768 + kt * 32 + c4);
      f16* dst = &sB[r * 40 + c4];
      dst[0] = (f16)v.x; dst[1] = (f16)v.y; dst[2] = (f16)v.z; dst[3] = (f16)v.w;
    }
    __syncthreads();
    f16x8 af[4], bf[4];
#pragma unroll
    for (int t = 0; t < 4; ++t) {
      af[t] = *(const f16x8*)&sA[(wm + t * 16 + frow) * 40 + fcol];
      bf[t] = *(const f16x8*)&sB[(wn + t * 16 + frow) * 40 + fcol];
    }
#pragma unroll
    for (int mt = 0; mt < 4; ++mt)
#pragma unroll
      for (int nt = 0; nt < 4; ++nt)
        acc[mt][nt] = MFMA16(af[mt], bf[nt], acc[mt][nt]);
    __syncthreads();
  }
#pragma unroll
  for (int mt = 0; mt < 4; ++mt) {
    int rbase = m0 + wm + mt * 16 + (lane >> 4) * 4;
#pragma unroll
    for (int nt = 0; nt < 4; ++nt) {
      int col = n0 + wn + nt * 16 + frow;
      float bv = bias[col];
#pragma unroll
      for (int rg = 0; rg < 4; ++rg) {
        int m = rbase + rg;
        if (m < kM) out[(size_t)m * 768 + col] = acc[mt][nt][rg] + bv;
      }
    }
  }
}

extern "C" void kernel_launch(void* const* d_in, const int* in_sizes, int n_in,
                              void* d_out, int out_size, void* d_ws, size_t ws_size,
                              hipStream_t stream) {
  if (ws_size < WS_TOTAL) return;
  const float* x      = (const float*)d_in[0];
  const float* qkv_w  = (const float*)d_in[1];
  const float* proj_w = (const float*)d_in[2];
  const float* proj_b = (const float*)d_in[3];
  const float* rph    = (const float*)d_in[4];
  const float* rpw    = (const float*)d_in[5];
  const float* rpt    = (const float*)d_in[6];
  char* ws = (char*)d_ws;
  f16* qf   = (f16*)(ws + OFF_Q);
  f16* qe   = (f16*)(ws + OFF_QE);
  f16* kf   = (f16*)(ws + OFF_K);
  f16* kone = (f16*)(ws + OFF_KONE);
  f16* vT   = (f16*)(ws + OFF_V);
  f16* Of   = (f16*)(ws + OFF_O);

  // no memset needed: every garbage-readable region is either multiplied by an
  // exact 0 in kone, masked by the validity slot, or guarded at the final store.
  arp_kone<<<(kNp * 64 + 255) / 256, 256, 0, stream>>>(kone);
  arp_gemm_qkv<<<dim3(18, 25), 256, 0, stream>>>(x, qkv_w, qf, kf, vT);
  int qeTot = 24 * kN * 37;
  arp_qext<<<(qeTot + 255) / 256, 256, 0, stream>>>(qf, rph, rpw, rpt, qe);
  arp_attn<<<dim3(25, 24), 256, 0, stream>>>(qf, qe, kf, kone, vT, Of);
  arp_gemm_proj<<<dim3(6, 25), 256, 0, stream>>>(Of, proj_w, proj_b, (float*)d_out);
}

// Round 4
// 293.492 us; speedup vs baseline: 1.1987x; 1.1987x over previous
//
#include <hip/hip_runtime.h>

using f16   = _Float16;
using f16x4 = __attribute__((ext_vector_type(4))) _Float16;
using f16x8 = __attribute__((ext_vector_type(8))) _Float16;
using f32x4 = __attribute__((ext_vector_type(4))) float;
using u32x4 = __attribute__((ext_vector_type(4))) unsigned int;
using fp16x2_raw = __fp16 __attribute__((ext_vector_type(2)));

#define MFMA16(a, b, c) __builtin_amdgcn_mfma_f32_16x16x32_f16((a), (b), (c), 0, 0, 0)

namespace {
constexpr int kT = 8, kWd = 14, kS = 196;
constexpr int kN = 1568;      // T*S (sequence length per batch)
constexpr int kM = 3136;      // B*N (GEMM rows)
constexpr int kHeads = 12;
constexpr int kNp = 1664;     // padded N (13*128)
// workspace byte offsets (all 256-aligned)
constexpr size_t OFF_Q    = 0;                       // qf  [24][Np][64] f16 (unscaled q)
constexpr size_t OFF_QE   = 5111808;                 // qe  [24][Np][64] f16 (rel ext, dims 0..36 valid)
constexpr size_t OFF_K    = 10223616;                // kf  [24][Np][64] f16 (k * 0.125)
constexpr size_t OFF_KONE = 15335424;                // kone[Np][64] f16 (one-hot ext, bh-independent)
constexpr size_t OFF_V    = 15548416;                // vT  [24][64][Np] f16
constexpr size_t OFF_O    = 20660224;                // Of  [3200][768] f16
constexpr size_t WS_TOTAL = 25575424;

__device__ inline f16x4 pack4(float4 v) {
  union { fp16x2_raw h2[2]; f16x4 f4; } u;
  u.h2[0] = __builtin_amdgcn_cvt_pkrtz(v.x, v.y);
  u.h2[1] = __builtin_amdgcn_cvt_pkrtz(v.z, v.w);
  return u.f4;
}
}

// ---------------- QKV GEMM: C[3136,2304] = X[3136,768] @ W[2304,768]^T ----------
// epilogue scatters q (unscaled), k*scale, v^T per head (f16, padded rows NOT zeroed)
__global__ __launch_bounds__(256) void arp_gemm_qkv(
    const float* __restrict__ X, const float* __restrict__ W,
    f16* __restrict__ qf, f16* __restrict__ kf, f16* __restrict__ vT) {
  __shared__ f16 sA[128 * 40];
  __shared__ f16 sB[128 * 40];
  const int tid = threadIdx.x, lane = tid & 63, wv = tid >> 6;
  const int m0 = blockIdx.y * 128, n0 = blockIdx.x * 128;
  const int wm = (wv & 1) * 64, wn = (wv >> 1) * 64;
  const int frow = lane & 15, fcol = (lane >> 4) * 8;
  const f32x4 vzero = {0.f, 0.f, 0.f, 0.f};
  f32x4 acc[4][4];
  for (int i = 0; i < 4; ++i)
    for (int j = 0; j < 4; ++j) acc[i][j] = vzero;

  for (int kt = 0; kt < 24; ++kt) {  // K=768, BK=32
#pragma unroll
    for (int i = 0; i < 4; ++i) {
      int idx = i * 256 + tid;
      int r = idx >> 3, c4 = (idx & 7) * 4;
      float4 v = {0.f, 0.f, 0.f, 0.f};
      int gm = m0 + r;
      if (gm < kM) v = *(const float4*)(X + (size_t)gm * 768 + kt * 32 + c4);
      *(f16x4*)&sA[r * 40 + c4] = pack4(v);
    }
#pragma unroll
    for (int i = 0; i < 4; ++i) {
      int idx = i * 256 + tid;
      int r = idx >> 3, c4 = (idx & 7) * 4;
      float4 v = *(const float4*)(W + (size_t)(n0 + r) * 768 + kt * 32 + c4);
      *(f16x4*)&sB[r * 40 + c4] = pack4(v);
    }
    __syncthreads();
    f16x8 af[4], bf[4];
#pragma unroll
    for (int t = 0; t < 4; ++t) {
      af[t] = *(const f16x8*)&sA[(wm + t * 16 + frow) * 40 + fcol];
      bf[t] = *(const f16x8*)&sB[(wn + t * 16 + frow) * 40 + fcol];
    }
#pragma unroll
    for (int mt = 0; mt < 4; ++mt)
#pragma unroll
      for (int nt = 0; nt < 4; ++nt)
        acc[mt][nt] = MFMA16(af[mt], bf[nt], acc[mt][nt]);
    __syncthreads();
  }
#pragma unroll
  for (int mt = 0; mt < 4; ++mt) {
    int rbase = m0 + wm + mt * 16 + (lane >> 4) * 4;
#pragma unroll
    for (int nt = 0; nt < 4; ++nt) {
      int col0 = n0 + wn + nt * 16;        // multiple of 16, uniform per nt
      int which = col0 / 768;
      int rem = col0 - which * 768;
      int hh = rem >> 6;
      int d = (rem & 63) + frow;
#pragma unroll
      for (int rg = 0; rg < 4; ++rg) {
        int m = rbase + rg;
        if (m < kM) {
          int b = (m >= kN) ? 1 : 0;
          int ns = m - b * kN;
          int bh = b * kHeads + hh;
          float av = acc[mt][nt][rg];
          if (which == 1) av *= 0.125f;      // fold softmax scale into K
          f16 hv = (f16)av;
          if (which == 0)      qf[((size_t)bh * kNp + ns) * 64 + d] = hv;
          else if (which == 1) kf[((size_t)bh * kNp + ns) * 64 + d] = hv;
          else                 vT[((size_t)bh * 64 + d) * kNp + ns] = hv;
        }
      }
    }
  }
}

// ---------------- K one-hot extension (bh-independent): kone[n][64] -------------
__global__ __launch_bounds__(256) void arp_kone(f16* __restrict__ kone) {
  int tid = blockIdx.x * 256 + threadIdx.x;
  if (tid >= kNp * 64) return;
  int n = tid >> 6, c = tid & 63;
  int t2 = n / kS; int rm = n - t2 * kS;
  int h2 = rm / kWd; int w2 = rm - h2 * kWd;
  if (t2 > kT - 1) t2 = kT - 1;
  float v = 0.f;
  if (c == h2) v = 1.f;
  else if (c == 14 + w2) v = 1.f;
  else if (c == 28 + t2) v = 1.f;
  else if (c == 36 && n >= kN) v = 1.f;
  kone[tid] = (f16)v;
}

// ---------------- Q extension: qe[bh][q][e] = q_vec . rel_pos[idx], e<36 --------
__global__ __launch_bounds__(256) void arp_qext(
    const f16* __restrict__ qf,
    const float* __restrict__ Rh, const float* __restrict__ Rw, const float* __restrict__ Rt,
    f16* __restrict__ qe) {
  int tid = blockIdx.x * 256 + threadIdx.x;
  const int TOT = 24 * kN * 37;
  if (tid >= TOT) return;
  int e = tid % 37;
  int rem = tid / 37;
  int q = rem % kN;
  int bh = rem / kN;
  f16* out = qe + ((size_t)bh * kNp + q) * 64;
  if (e == 36) { out[36] = (f16)(-10000.f); return; }
  int tq = q / kS, sr = q - tq * kS;
  int hq = sr / kWd, wq = sr - hq * kWd;
  const float* R;
  if (e < 14)      R = Rh + (hq - e + 13) * 64;
  else if (e < 28) R = Rw + (wq - (e - 14) + 13) * 64;
  else             R = Rt + (tq - (e - 28) + 7) * 64;
  const f16x8* qv = (const f16x8*)(qf + ((size_t)bh * kNp + q) * 64);
  const float4* R4 = (const float4*)R;
  float sum = 0.f;
#pragma unroll
  for (int i = 0; i < 8; ++i) {
    f16x8 qh = qv[i];
    float4 a = R4[i * 2], b = R4[i * 2 + 1];
    sum += (float)qh[0] * a.x + (float)qh[1] * a.y + (float)qh[2] * a.z + (float)qh[3] * a.w
         + (float)qh[4] * b.x + (float)qh[5] * b.y + (float)qh[6] * b.z + (float)qh[7] * b.w;
  }
  out[e] = (f16)sum;
}

// ---------------- flash attention, bias folded into QK^T via ext dims -----------
// grid (25 q-tiles of 64, 24 bh); K_ext = 128 dims -> 4 MFMA k-steps.
// LDS: sK 34816 + sV 17408 = 52224 B -> 3 blocks/CU (600 blocks all co-resident).
// P round-trip buffer ALIASES sK rows (wave wv owns rows wv*16..wv*16+15);
// barrier C separates all QK-phase sK reads from the P writes.
__global__ __launch_bounds__(256, 3) void arp_attn(
    const f16* __restrict__ qf, const f16* __restrict__ qe,
    const f16* __restrict__ kf, const f16* __restrict__ kone,
    const f16* __restrict__ vT, f16* __restrict__ Of) {
  __shared__ f16 sK[128 * 136];       // [key][136] valid 128 (64 k + 64 ext)
  __shared__ f16 sV[64 * 136];        // [d][136] valid 128

  const int tid = threadIdx.x, lane = tid & 63, wv = tid >> 6;
  const int q0 = blockIdx.x * 64;
  const int bh = blockIdx.y;
  const int b = bh / kHeads, hh = bh - b * kHeads;
  const int frow = lane & 15, quad = lane >> 4;
  const f32x4 vzero = {0.f, 0.f, 0.f, 0.f};

  // persistent Q_ext fragments (A-layout), rows q0 + wv*16 + frow
  f16x8 aQ[4];
  {
    int row = q0 + wv * 16 + frow;
    const f16* qp = qf + ((size_t)bh * kNp + row) * 64;
    aQ[0] = *(const f16x8*)(qp + quad * 8);
    aQ[1] = *(const f16x8*)(qp + 32 + quad * 8);
    const f16* ep = qe + ((size_t)bh * kNp + row) * 64;
    aQ[2] = *(const f16x8*)(ep + quad * 8);
    aQ[3] = *(const f16x8*)(ep + 32 + quad * 8);
  }
  float m_i[4], l_i[4], alpha[4];
  f32x4 Oc[4];
#pragma unroll
  for (int r = 0; r < 4; ++r) { m_i[r] = -__builtin_inff(); l_i[r] = 0.f; }
#pragma unroll
  for (int t = 0; t < 4; ++t) Oc[t] = vzero;

  for (int kt = 0; kt < 13; ++kt) {
    __syncthreads();  // A: prior tile's P/V reads complete before restaging
    // stage K_ext tile [128][128] -> sK (cols 0..63 from kf, 64..127 from kone)
#pragma unroll
    for (int i = 0; i < 8; ++i) {
      int idx = i * 256 + tid;
      int r = idx >> 4, ch = idx & 15;
      const f16* src = (ch < 8)
          ? kf + ((size_t)bh * kNp + kt * 128 + r) * 64 + ch * 8
          : kone + (size_t)(kt * 128 + r) * 64 + (ch - 8) * 8;
      *(u32x4*)&sK[r * 136 + ch * 8] = *(const u32x4*)src;
    }
    // stage V^T tile [64][128] -> sV (coalesced 256-B rows)
#pragma unroll
    for (int i = 0; i < 4; ++i) {
      int idx = i * 256 + tid;
      int r = idx >> 4, c8 = (idx & 15) * 8;
      u32x4 v = *(const u32x4*)(vT + ((size_t)bh * 64 + r) * kNp + kt * 128 + c8);
      *(u32x4*)&sV[r * 136 + c8] = v;
    }
    __syncthreads();  // B: staging visible

    // QK^T + bias in one shot: S[16 x 128] per wave, K=128
    f32x4 Sc[8];
#pragma unroll
    for (int nt = 0; nt < 8; ++nt) {
      const f16* kb = &sK[(nt * 16 + frow) * 136 + quad * 8];
      f32x4 s = MFMA16(aQ[0], *(const f16x8*)(kb), vzero);
      s = MFMA16(aQ[1], *(const f16x8*)(kb + 32), s);
      s = MFMA16(aQ[2], *(const f16x8*)(kb + 64), s);
      Sc[nt] = MFMA16(aQ[3], *(const f16x8*)(kb + 96), s);
    }
    // online softmax per row (scale+bias+mask already inside Sc)
    float pv[8][4];
#pragma unroll
    for (int nt = 0; nt < 8; ++nt)
#pragma unroll
      for (int r = 0; r < 4; ++r) pv[nt][r] = Sc[nt][r];
#pragma unroll
    for (int r = 0; r < 4; ++r) {
      float mx = pv[0][r];
#pragma unroll
      for (int nt = 1; nt < 8; ++nt) mx = fmaxf(mx, pv[nt][r]);
#pragma unroll
      for (int off = 1; off < 16; off <<= 1) mx = fmaxf(mx, __shfl_xor(mx, off, 64));
      float mn = fmaxf(m_i[r], mx);
      alpha[r] = __expf(m_i[r] - mn);
      m_i[r] = mn;
      float rs = 0.f;
#pragma unroll
      for (int nt = 0; nt < 8; ++nt) {
        float p = __expf(pv[nt][r] - mn);
        pv[nt][r] = p;
        rs += p;
      }
#pragma unroll
      for (int off = 1; off < 16; off <<= 1) rs += __shfl_xor(rs, off, 64);
      l_i[r] = l_i[r] * alpha[r] + rs;
    }
#pragma unroll
    for (int t = 0; t < 4; ++t) {
      Oc[t][0] *= alpha[0]; Oc[t][1] *= alpha[1];
      Oc[t][2] *= alpha[2]; Oc[t][3] *= alpha[3];
    }
    __syncthreads();  // C: all QK-phase sK reads done; safe to clobber with P
    // P: C-layout -> sK rows [wv*16 .. wv*16+16) -> A-layout (intra-wave dep only)
    f16* sP = &sK[wv * 16 * 136];
#pragma unroll
    for (int nt = 0; nt < 8; ++nt)
#pragma unroll
      for (int r = 0; r < 4; ++r)
        sP[(quad * 4 + r) * 136 + nt * 16 + frow] = (f16)pv[nt][r];
    // PV: O[16 x 64] += P[16 x 128] @ V[128 x 64]
#pragma unroll
    for (int kc = 0; kc < 4; ++kc) {
      f16x8 aP = *(const f16x8*)&sP[frow * 136 + kc * 32 + quad * 8];
#pragma unroll
      for (int t = 0; t < 4; ++t) {
        f16x8 bV = *(const f16x8*)&sV[(t * 16 + frow) * 136 + kc * 32 + quad * 8];
        Oc[t] = MFMA16(aP, bV, Oc[t]);
      }
    }
  }
  // epilogue: normalize and store O[b*N+row][hh*64 + d] as f16
#pragma unroll
  for (int t = 0; t < 4; ++t)
#pragma unroll
    for (int r = 0; r < 4; ++r) {
      int row = q0 + wv * 16 + quad * 4 + r;
      if (row < kN) {
        float val = Oc[t][r] / l_i[r];
        Of[((size_t)(b * kN + row)) * 768 + hh * 64 + t * 16 + frow] = (f16)val;
      }
    }
}

// ---------------- proj GEMM: out[3136,768] = O[3136,768] @ Wp[768,768]^T + bias --
__global__ __launch_bounds__(256) void arp_gemm_proj(
    const f16* __restrict__ A, const float* __restrict__ W,
    const float* __restrict__ bias, float* __restrict__ out) {
  __shared__ f16 sA[128 * 40];
  __shared__ f16 sB[128 * 40];
  const int tid = threadIdx.x, lane = tid & 63, wv = tid >> 6;
  const int m0 = blockIdx.y * 128, n0 = blockIdx.x * 128;
  const int wm = (wv & 1) * 64, wn = (wv >> 1) * 64;
  const int frow = lane & 15, fcol = (lane >> 4) * 8;
  const f32x4 vzero = {0.f, 0.f, 0.f, 0.f};
  f32x4 acc[4][4];
  for (int i = 0; i < 4; ++i)
    for (int j = 0; j < 4; ++j) acc[i][j] = vzero;

  for (int kt = 0; kt < 24; ++kt) {
#pragma unroll
    for (int i = 0; i < 2; ++i) {
      int idx = i * 256 + tid;
      int r = idx >> 2, c8 = (idx & 3) * 8;
      u32x4 v = *(const u32x4*)(A + (size_t)(m0 + r) * 768 + kt * 32 + c8);
      *(u32x4*)&sA[r * 40 + c8] = v;
    }
#pragma unroll
    for (int i = 0; i < 4; ++i) {
      int idx = i * 256 + tid;
      int r = idx >> 3, c4 = (idx & 7) * 4;
      float4 v = *(const float4*)(W + (size_t)(n0 + r) * 768 + kt * 32 + c4);
      *(f16x4*)&sB[r * 40 + c4] = pack4(v);
    }
    __syncthreads();
    f16x8 af[4], bf[4];
#pragma unroll
    for (int t = 0; t < 4; ++t) {
      af[t] = *(const f16x8*)&sA[(wm + t * 16 + frow) * 40 + fcol];
      bf[t] = *(const f16x8*)&sB[(wn + t * 16 + frow) * 40 + fcol];
    }
#pragma unroll
    for (int mt = 0; mt < 4; ++mt)
#pragma unroll
      for (int nt = 0; nt < 4; ++nt)
        acc[mt][nt] = MFMA16(af[mt], bf[nt], acc[mt][nt]);
    __syncthreads();
  }
#pragma unroll
  for (int mt = 0; mt < 4; ++mt) {
    int rbase = m0 + wm + mt * 16 + (lane >> 4) * 4;
#pragma unroll
    for (int nt = 0; nt < 4; ++nt) {
      int col = n0 + wn + nt * 16 + frow;
      float bv = bias[col];
#pragma unroll
      for (int rg = 0; rg < 4; ++rg) {
        int m = rbase + rg;
        if (m < kM) out[(size_t)m * 768 + col] = acc[mt][nt][rg] + bv;
      }
    }
  }
}

extern "C" void kernel_launch(void* const* d_in, const int* in_sizes, int n_in,
                              void* d_out, int out_size, void* d_ws, size_t ws_size,
                              hipStream_t stream) {
  if (ws_size < WS_TOTAL) return;
  const float* x      = (const float*)d_in[0];
  const float* qkv_w  = (const float*)d_in[1];
  const float* proj_w = (const float*)d_in[2];
  const float* proj_b = (const float*)d_in[3];
  const float* rph    = (const float*)d_in[4];
  const float* rpw    = (const float*)d_in[5];
  const float* rpt    = (const float*)d_in[6];
  char* ws = (char*)d_ws;
  f16* qf   = (f16*)(ws + OFF_Q);
  f16* qe   = (f16*)(ws + OFF_QE);
  f16* kf   = (f16*)(ws + OFF_K);
  f16* kone = (f16*)(ws + OFF_KONE);
  f16* vT   = (f16*)(ws + OFF_V);
  f16* Of   = (f16*)(ws + OFF_O);

  arp_kone<<<(kNp * 64 + 255) / 256, 256, 0, stream>>>(kone);
  arp_gemm_qkv<<<dim3(18, 25), 256, 0, stream>>>(x, qkv_w, qf, kf, vT);
  int qeTot = 24 * kN * 37;
  arp_qext<<<(qeTot + 255) / 256, 256, 0, stream>>>(qf, rph, rpw, rpt, qe);
  arp_attn<<<dim3(25, 24), 256, 0, stream>>>(qf, qe, kf, kone, vT, Of);
  arp_gemm_proj<<<dim3(6, 25), 256, 0, stream>>>(Of, proj_w, proj_b, (float*)d_out);
}

// Round 5
// 292.530 us; speedup vs baseline: 1.2027x; 1.0033x over previous
//
#include <hip/hip_runtime.h>

using f16   = _Float16;
using f16x4 = __attribute__((ext_vector_type(4))) _Float16;
using f16x8 = __attribute__((ext_vector_type(8))) _Float16;
using f32x4 = __attribute__((ext_vector_type(4))) float;
using u32x4 = __attribute__((ext_vector_type(4))) unsigned int;
using fp16x2_raw = __fp16 __attribute__((ext_vector_type(2)));

#define MFMA16(a, b, c) __builtin_amdgcn_mfma_f32_16x16x32_f16((a), (b), (c), 0, 0, 0)

namespace {
constexpr int kT = 8, kWd = 14, kS = 196;
constexpr int kN = 1568;      // T*S (sequence length per batch)
constexpr int kM = 3136;      // B*N (GEMM rows)
constexpr int kHeads = 12;
constexpr int kNp = 1664;     // padded N (13*128)
// workspace byte offsets (all 256-aligned)
constexpr size_t OFF_Q    = 0;            // qf  [24][Np][64] f16 (unscaled q)
constexpr size_t OFF_QE   = 5111808;      // qe  [24][Np][32] f16 (relH/relW dots + mask slot)
constexpr size_t OFF_QET  = 7667712;      // qet [24][Np][8]  f32 (relT dots)
constexpr size_t OFF_K    = 8945664;      // kf  [24][Np][64] f16 (k * 0.125)
constexpr size_t OFF_KONE = 14057472;     // kone[Np][32] f16 (one-hot h/w + validity)
constexpr size_t OFF_V    = 14163968;     // vT  [24][64][Np] f16
constexpr size_t OFF_O    = 19275776;     // Of  [3200][768] f16
constexpr size_t WS_TOTAL = 24190976;

__device__ inline f16x4 pack4(float4 v) {
  union { fp16x2_raw h2[2]; f16x4 f4; } u;
  u.h2[0] = __builtin_amdgcn_cvt_pkrtz(v.x, v.y);
  u.h2[1] = __builtin_amdgcn_cvt_pkrtz(v.z, v.w);
  return u.f4;
}
}

// ---------------- QKV GEMM: C[3136,2304] = X[3136,768] @ W[2304,768]^T ----------
// q (unscaled), k*scale stored direct; v^T stored via LDS transpose (coalesced).
__global__ __launch_bounds__(256) void arp_gemm_qkv(
    const float* __restrict__ X, const float* __restrict__ W,
    f16* __restrict__ qf, f16* __restrict__ kf, f16* __restrict__ vT) {
  __shared__ f16 sA[128 * 40];
  __shared__ f16 sB[128 * 40];
  __shared__ f16 sE[128 * 136];   // transpose staging for v-blocks
  const int tid = threadIdx.x, lane = tid & 63, wv = tid >> 6;
  const int m0 = blockIdx.y * 128, n0 = blockIdx.x * 128;
  const int wm = (wv & 1) * 64, wn = (wv >> 1) * 64;
  const int frow = lane & 15, quad = lane >> 4, fcol = quad * 8;
  const f32x4 vzero = {0.f, 0.f, 0.f, 0.f};
  f32x4 acc[4][4];
  for (int i = 0; i < 4; ++i)
    for (int j = 0; j < 4; ++j) acc[i][j] = vzero;

  for (int kt = 0; kt < 24; ++kt) {  // K=768, BK=32
#pragma unroll
    for (int i = 0; i < 4; ++i) {
      int idx = i * 256 + tid;
      int r = idx >> 3, c4 = (idx & 7) * 4;
      float4 v = {0.f, 0.f, 0.f, 0.f};
      int gm = m0 + r;
      if (gm < kM) v = *(const float4*)(X + (size_t)gm * 768 + kt * 32 + c4);
      *(f16x4*)&sA[r * 40 + c4] = pack4(v);
    }
#pragma unroll
    for (int i = 0; i < 4; ++i) {
      int idx = i * 256 + tid;
      int r = idx >> 3, c4 = (idx & 7) * 4;
      float4 v = *(const float4*)(W + (size_t)(n0 + r) * 768 + kt * 32 + c4);
      *(f16x4*)&sB[r * 40 + c4] = pack4(v);
    }
    __syncthreads();
    f16x8 af[4], bf[4];
#pragma unroll
    for (int t = 0; t < 4; ++t) {
      af[t] = *(const f16x8*)&sA[(wm + t * 16 + frow) * 40 + fcol];
      bf[t] = *(const f16x8*)&sB[(wn + t * 16 + frow) * 40 + fcol];
    }
#pragma unroll
    for (int mt = 0; mt < 4; ++mt)
#pragma unroll
      for (int nt = 0; nt < 4; ++nt)
        acc[mt][nt] = MFMA16(af[mt], bf[nt], acc[mt][nt]);
    __syncthreads();
  }

  if (n0 >= 1536) {
    // ---- v-block: C cols are v; transpose through LDS, store vT coalesced ----
#pragma unroll
    for (int mt = 0; mt < 4; ++mt)
#pragma unroll
      for (int nt = 0; nt < 4; ++nt) {
        int cl = wn + nt * 16 + frow;          // col_local 0..127
#pragma unroll
        for (int rg = 0; rg < 4; ++rg) {
          int rl = wm + mt * 16 + quad * 4 + rg;  // row_local 0..127
          sE[cl * 136 + rl] = (f16)acc[mt][nt][rg];
        }
      }
    __syncthreads();
    int cl = tid >> 1;
    int rb = (tid & 1) * 64;
    int rem = n0 + cl - 1536;
    int hh = rem >> 6, d = rem & 63;
#pragma unroll
    for (int j = 0; j < 8; ++j) {
      int ms = m0 + rb + j * 8;                // 8 consecutive m, same batch side
      if (ms < kM) {
        int bb = (ms >= kN) ? 1 : 0;
        int ns = ms - bb * kN;
        int bh = bb * kHeads + hh;
        *(u32x4*)(vT + ((size_t)bh * 64 + d) * kNp + ns) =
            *(const u32x4*)&sE[cl * 136 + rb + j * 8];
      }
    }
  } else {
    // ---- q/k block: direct stores (rows of [n][64] per head) ----
#pragma unroll
    for (int mt = 0; mt < 4; ++mt) {
      int rbase = m0 + wm + mt * 16 + quad * 4;
#pragma unroll
      for (int nt = 0; nt < 4; ++nt) {
        int col0 = n0 + wn + nt * 16;
        int which = col0 / 768;
        int rem = col0 - which * 768;
        int hh = rem >> 6;
        int d = (rem & 63) + frow;
#pragma unroll
        for (int rg = 0; rg < 4; ++rg) {
          int m = rbase + rg;
          if (m < kM) {
            int bb = (m >= kN) ? 1 : 0;
            int ns = m - bb * kN;
            int bh = bb * kHeads + hh;
            float av = acc[mt][nt][rg];
            if (which == 1) av *= 0.125f;      // fold softmax scale into K
            f16 hv = (f16)av;
            if (which == 0) qf[((size_t)bh * kNp + ns) * 64 + d] = hv;
            else            kf[((size_t)bh * kNp + ns) * 64 + d] = hv;
          }
        }
      }
    }
  }
}

// ---------------- K one-hot extension (bh-independent): kone[n][32] -------------
// 0..13 = onehot(h2), 14..27 = onehot(w2), 28 = 1 if padded key, 29..31 = 0
__global__ __launch_bounds__(256) void arp_kone(f16* __restrict__ kone) {
  int tid = blockIdx.x * 256 + threadIdx.x;
  if (tid >= kNp * 32) return;
  int n = tid >> 5, c = tid & 31;
  int t2 = n / kS; int rm = n - t2 * kS;
  int h2 = rm / kWd; int w2 = rm - h2 * kWd;
  float v = 0.f;
  if (c == h2) v = 1.f;
  else if (c == 14 + w2) v = 1.f;
  else if (c == 28 && n >= kN) v = 1.f;
  kone[tid] = (f16)v;
}

// ---------------- Q extension: relH/relW dots -> qe (f16), relT dots -> qet (f32)
__global__ __launch_bounds__(256) void arp_qext(
    const f16* __restrict__ qf,
    const float* __restrict__ Rh, const float* __restrict__ Rw, const float* __restrict__ Rt,
    f16* __restrict__ qe, float* __restrict__ qet) {
  int tid = blockIdx.x * 256 + threadIdx.x;
  const int TOT = 24 * kN * 36;
  if (tid >= TOT) return;
  int e = tid % 36;
  int rem = tid / 36;
  int q = rem % kN;
  int bh = rem / kN;
  int tq = q / kS, sr = q - tq * kS;
  int hq = sr / kWd, wq = sr - hq * kWd;
  const float* R;
  int t2 = 0; bool isT = false;
  if (e < 14)      R = Rh + (hq - e + 13) * 64;
  else if (e < 28) R = Rw + (wq - (e - 14) + 13) * 64;
  else { isT = true; t2 = e - 28; R = Rt + (tq - t2 + 7) * 64; }
  const f16x8* qv = (const f16x8*)(qf + ((size_t)bh * kNp + q) * 64);
  const float4* R4 = (const float4*)R;
  float sum = 0.f;
#pragma unroll
  for (int i = 0; i < 8; ++i) {
    f16x8 qh = qv[i];
    float4 a = R4[i * 2], b = R4[i * 2 + 1];
    sum += (float)qh[0] * a.x + (float)qh[1] * a.y + (float)qh[2] * a.z + (float)qh[3] * a.w
         + (float)qh[4] * b.x + (float)qh[5] * b.y + (float)qh[6] * b.z + (float)qh[7] * b.w;
  }
  if (isT) qet[((size_t)bh * kNp + q) * 8 + t2] = sum;
  else     qe[((size_t)bh * kNp + q) * 32 + e] = (f16)sum;
  if (e == 0) {
    f16* o = qe + ((size_t)bh * kNp + q) * 32;
    o[28] = (f16)(-10000.f); o[29] = (f16)0.f; o[30] = (f16)0.f; o[31] = (f16)0.f;
  }
}

// ---------------- flash attention: TQ=128 (32 q-rows/wave), 96-dim QK^T ---------
// grid (13 q-tiles, 24 bh). Ext dims: 64 q + 32 (h/w one-hot + mask) = 3 MFMA steps;
// rel_t added post-MFMA (<=2 distinct t2 per 128-key tile -> cndmask).
// LDS: sK 128x136 (96 staged; doubles as P buffer) + sV 64x136 + sQT = 56320 B.
__global__ __launch_bounds__(256, 2) void arp_attn(
    const f16* __restrict__ qf, const f16* __restrict__ qe, const float* __restrict__ qet,
    const f16* __restrict__ kf, const f16* __restrict__ kone,
    const f16* __restrict__ vT, f16* __restrict__ Of) {
  __shared__ f16 sK[128 * 136];
  __shared__ f16 sV[64 * 136];
  __shared__ float sQT[128 * 8];

  const int tid = threadIdx.x, lane = tid & 63, wv = tid >> 6;
  const int q0 = blockIdx.x * 128;
  const int bh = blockIdx.y;
  const int b = bh / kHeads, hh = bh - b * kHeads;
  const int frow = lane & 15, quad = lane >> 4;
  const f32x4 vzero = {0.f, 0.f, 0.f, 0.f};

  {  // stage per-q-row rel_t table once (128 rows x 8 f32)
    int row = tid >> 1, part = tid & 1;
    *(float4*)&sQT[row * 8 + part * 4] =
        *(const float4*)(qet + ((size_t)bh * kNp + q0 + row) * 8 + part * 4);
  }
  // persistent Q fragments: 2 row-tiles of 16 per wave
  f16x8 aQ[2][2], aQE[2];
#pragma unroll
  for (int t = 0; t < 2; ++t) {
    int row = q0 + wv * 32 + t * 16 + frow;
    const f16* qp = qf + ((size_t)bh * kNp + row) * 64;
    aQ[t][0] = *(const f16x8*)(qp + quad * 8);
    aQ[t][1] = *(const f16x8*)(qp + 32 + quad * 8);
    aQE[t] = *(const f16x8*)(qe + ((size_t)bh * kNp + row) * 32 + quad * 8);
  }
  float m_i[2][4], l_i[2][4];
  f32x4 Oc[2][4];
#pragma unroll
  for (int t = 0; t < 2; ++t)
#pragma unroll
    for (int r = 0; r < 4; ++r) { m_i[t][r] = -__builtin_inff(); l_i[t][r] = 0.f; Oc[t][r] = vzero; }

  for (int kt = 0; kt < 13; ++kt) {
    __syncthreads();  // A: prior tile's P/V reads done before restaging
    // stage sK: 128 rows x 96 cols (0..63 kf, 64..95 kone)
#pragma unroll
    for (int i = 0; i < 6; ++i) {
      int idx = i * 256 + tid;
      int r = idx / 12, c = (idx - r * 12) * 8;
      const f16* src = (c < 64)
          ? kf + ((size_t)bh * kNp + kt * 128 + r) * 64 + c
          : kone + (size_t)(kt * 128 + r) * 32 + (c - 64);
      *(u32x4*)&sK[r * 136 + c] = *(const u32x4*)src;
    }
    // stage sV: 64 d-rows x 128 keys
#pragma unroll
    for (int i = 0; i < 4; ++i) {
      int idx = i * 256 + tid;
      int r = idx >> 4, c8 = (idx & 15) * 8;
      *(u32x4*)&sV[r * 136 + c8] =
          *(const u32x4*)(vT + ((size_t)bh * 64 + r) * kNp + kt * 128 + c8);
    }
    __syncthreads();  // B

    // rel_t values for this k-tile (<=2 distinct t2)
    const int base = kt * 128;
    const int t2lo = base / kS;
    int t2hi = (base + 127) / kS; if (t2hi > kT - 1) t2hi = kT - 1;
    const int jb = (t2lo + 1) * kS;   // keys >= jb use t2hi
    float vlo[2][4], vhi[2][4];
#pragma unroll
    for (int t = 0; t < 2; ++t)
#pragma unroll
      for (int r = 0; r < 4; ++r) {
        int rl = wv * 32 + t * 16 + quad * 4 + r;
        vlo[t][r] = sQT[rl * 8 + t2lo];
        vhi[t][r] = sQT[rl * 8 + t2hi];
      }

    // QK^T + bias(h,w,mask): 96 dims = 3 MFMA steps, both row-tiles share B-frags
    f32x4 Sc[2][8];
#pragma unroll
    for (int nt = 0; nt < 8; ++nt) {
      const f16* kb = &sK[(nt * 16 + frow) * 136 + quad * 8];
      f16x8 kb0 = *(const f16x8*)(kb);
      f16x8 kb1 = *(const f16x8*)(kb + 32);
      f16x8 kbe = *(const f16x8*)(kb + 64);
#pragma unroll
      for (int t = 0; t < 2; ++t) {
        f32x4 s = MFMA16(aQ[t][0], kb0, vzero);
        s = MFMA16(aQ[t][1], kb1, s);
        Sc[t][nt] = MFMA16(aQE[t], kbe, s);
      }
    }
    __syncthreads();  // C: all QK-phase sK reads done; safe to clobber with P

    f16* sPw = &sK[(size_t)wv * 32 * 136];
#pragma unroll
    for (int t = 0; t < 2; ++t) {
      // add rel_t
#pragma unroll
      for (int nt = 0; nt < 8; ++nt) {
        int jg = base + nt * 16 + frow;
        bool lo = jg < jb;
#pragma unroll
        for (int r = 0; r < 4; ++r)
          Sc[t][nt][r] += lo ? vlo[t][r] : vhi[t][r];
      }
      // online softmax (rows = quad*4+r, 16-lane butterfly over frow)
      float alpha[4];
#pragma unroll
      for (int r = 0; r < 4; ++r) {
        float mx = Sc[t][0][r];
#pragma unroll
        for (int nt = 1; nt < 8; ++nt) mx = fmaxf(mx, Sc[t][nt][r]);
#pragma unroll
        for (int off = 1; off < 16; off <<= 1) mx = fmaxf(mx, __shfl_xor(mx, off, 64));
        float mn = fmaxf(m_i[t][r], mx);
        alpha[r] = __expf(m_i[t][r] - mn);
        m_i[t][r] = mn;
        float rs = 0.f;
#pragma unroll
        for (int nt = 0; nt < 8; ++nt) {
          float p = __expf(Sc[t][nt][r] - mn);
          Sc[t][nt][r] = p;
          rs += p;
        }
#pragma unroll
        for (int off = 1; off < 16; off <<= 1) rs += __shfl_xor(rs, off, 64);
        l_i[t][r] = l_i[t][r] * alpha[r] + rs;
      }
#pragma unroll
      for (int td = 0; td < 4; ++td) {
        Oc[t][td][0] *= alpha[0]; Oc[t][td][1] *= alpha[1];
        Oc[t][td][2] *= alpha[2]; Oc[t][td][3] *= alpha[3];
      }
      // P: C-layout -> own sK rows (A-layout for PV)
#pragma unroll
      for (int nt = 0; nt < 8; ++nt)
#pragma unroll
        for (int r = 0; r < 4; ++r)
          sPw[(t * 16 + quad * 4 + r) * 136 + nt * 16 + frow] = (f16)Sc[t][nt][r];
    }
    // PV: O[32 x 64] += P[32 x 128] @ V[128 x 64]; bV shared across row-tiles
#pragma unroll
    for (int kc = 0; kc < 4; ++kc) {
      f16x8 bV[4];
#pragma unroll
      for (int td = 0; td < 4; ++td)
        bV[td] = *(const f16x8*)&sV[(td * 16 + frow) * 136 + kc * 32 + quad * 8];
#pragma unroll
      for (int t = 0; t < 2; ++t) {
        f16x8 aP = *(const f16x8*)&sPw[(t * 16 + frow) * 136 + kc * 32 + quad * 8];
#pragma unroll
        for (int td = 0; td < 4; ++td)
          Oc[t][td] = MFMA16(aP, bV[td], Oc[t][td]);
      }
    }
  }
  // epilogue
#pragma unroll
  for (int t = 0; t < 2; ++t)
#pragma unroll
    for (int td = 0; td < 4; ++td)
#pragma unroll
      for (int r = 0; r < 4; ++r) {
        int row = q0 + wv * 32 + t * 16 + quad * 4 + r;
        if (row < kN) {
          float val = Oc[t][td][r] / l_i[t][r];
          Of[((size_t)(b * kN + row)) * 768 + hh * 64 + td * 16 + frow] = (f16)val;
        }
      }
}

// ---------------- proj GEMM: out[3136,768] = O[3136,768] @ Wp[768,768]^T + bias --
__global__ __launch_bounds__(256) void arp_gemm_proj(
    const f16* __restrict__ A, const float* __restrict__ W,
    const float* __restrict__ bias, float* __restrict__ out) {
  __shared__ f16 sA[128 * 40];
  __shared__ f16 sB[128 * 40];
  const int tid = threadIdx.x, lane = tid & 63, wv = tid >> 6;
  const int m0 = blockIdx.y * 128, n0 = blockIdx.x * 128;
  const int wm = (wv & 1) * 64, wn = (wv >> 1) * 64;
  const int frow = lane & 15, fcol = (lane >> 4) * 8;
  const f32x4 vzero = {0.f, 0.f, 0.f, 0.f};
  f32x4 acc[4][4];
  for (int i = 0; i < 4; ++i)
    for (int j = 0; j < 4; ++j) acc[i][j] = vzero;

  for (int kt = 0; kt < 24; ++kt) {
#pragma unroll
    for (int i = 0; i < 2; ++i) {
      int idx = i * 256 + tid;
      int r = idx >> 2, c8 = (idx & 3) * 8;
      u32x4 v = *(const u32x4*)(A + (size_t)(m0 + r) * 768 + kt * 32 + c8);
      *(u32x4*)&sA[r * 40 + c8] = v;
    }
#pragma unroll
    for (int i = 0; i < 4; ++i) {
      int idx = i * 256 + tid;
      int r = idx >> 3, c4 = (idx & 7) * 4;
      float4 v = *(const float4*)(W + (size_t)(n0 + r) * 768 + kt * 32 + c4);
      *(f16x4*)&sB[r * 40 + c4] = pack4(v);
    }
    __syncthreads();
    f16x8 af[4], bf[4];
#pragma unroll
    for (int t = 0; t < 4; ++t) {
      af[t] = *(const f16x8*)&sA[(wm + t * 16 + frow) * 40 + fcol];
      bf[t] = *(const f16x8*)&sB[(wn + t * 16 + frow) * 40 + fcol];
    }
#pragma unroll
    for (int mt = 0; mt < 4; ++mt)
#pragma unroll
      for (int nt = 0; nt < 4; ++nt)
        acc[mt][nt] = MFMA16(af[mt], bf[nt], acc[mt][nt]);
    __syncthreads();
  }
#pragma unroll
  for (int mt = 0; mt < 4; ++mt) {
    int rbase = m0 + wm + mt * 16 + (lane >> 4) * 4;
#pragma unroll
    for (int nt = 0; nt < 4; ++nt) {
      int col = n0 + wn + nt * 16 + frow;
      float bv = bias[col];
#pragma unroll
      for (int rg = 0; rg < 4; ++rg) {
        int m = rbase + rg;
        if (m < kM) out[(size_t)m * 768 + col] = acc[mt][nt][rg] + bv;
      }
    }
  }
}

extern "C" void kernel_launch(void* const* d_in, const int* in_sizes, int n_in,
                              void* d_out, int out_size, void* d_ws, size_t ws_size,
                              hipStream_t stream) {
  if (ws_size < WS_TOTAL) return;
  const float* x      = (const float*)d_in[0];
  const float* qkv_w  = (const float*)d_in[1];
  const float* proj_w = (const float*)d_in[2];
  const float* proj_b = (const float*)d_in[3];
  const float* rph    = (const float*)d_in[4];
  const float* rpw    = (const float*)d_in[5];
  const float* rpt    = (const float*)d_in[6];
  char* ws = (char*)d_ws;
  f16*   qf   = (f16*)(ws + OFF_Q);
  f16*   qe   = (f16*)(ws + OFF_QE);
  float* qet  = (float*)(ws + OFF_QET);
  f16*   kf   = (f16*)(ws + OFF_K);
  f16*   kone = (f16*)(ws + OFF_KONE);
  f16*   vT   = (f16*)(ws + OFF_V);
  f16*   Of   = (f16*)(ws + OFF_O);

  arp_kone<<<(kNp * 32 + 255) / 256, 256, 0, stream>>>(kone);
  arp_gemm_qkv<<<dim3(18, 25), 256, 0, stream>>>(x, qkv_w, qf, kf, vT);
  int qeTot = 24 * kN * 36;
  arp_qext<<<(qeTot + 255) / 256, 256, 0, stream>>>(qf, rph, rpw, rpt, qe, qet);
  arp_attn<<<dim3(13, 24), 256, 0, stream>>>(qf, qe, qet, kf, kone, vT, Of);
  arp_gemm_proj<<<dim3(6, 25), 256, 0, stream>>>(Of, proj_w, proj_b, (float*)d_out);
}